// Round 6
// baseline (405.478 us; speedup 1.0000x reference)
//
#include <hip/hip_runtime.h>
#include <math.h>

#define B_ 16
#define S_ 512
#define D_ 768
#define H_ 12
#define DH_ 64
#define BH_ (B_*H_)     // 192
#define MTOT (B_*S_)    // 8192
#define NTOT (3*D_)     // 2304

typedef unsigned short ushort_t;
typedef __attribute__((ext_vector_type(8))) short bf16x8;
typedef __attribute__((ext_vector_type(4))) float f32x4;

__device__ __forceinline__ unsigned short f2bf(float x){
    unsigned u = __float_as_uint(x);
    unsigned r = (u + 0x7FFFu + ((u >> 16) & 1u)) >> 16;
    return (unsigned short)r;
}
__device__ __forceinline__ float bf2f(unsigned short b){
    return __uint_as_float(((unsigned)b) << 16);
}

__device__ __forceinline__ void cp16(const void* g, void* l){
    __builtin_amdgcn_global_load_lds(
        (const __attribute__((address_space(1))) unsigned int*)g,
        (__attribute__((address_space(3))) unsigned int*)l, 16, 0, 0);
}

// ---------------------------------------------------------------------------
// f32 -> (hi, lo) bf16 split conversion, 4 elems/thread
// ---------------------------------------------------------------------------
__global__ __launch_bounds__(256)
void convert_hl(const float* __restrict__ src, ushort_t* __restrict__ hi,
                ushort_t* __restrict__ lo, int n4)
{
    int i = blockIdx.x * 256 + threadIdx.x;
    if (i >= n4) return;
    float4 x = ((const float4*)src)[i];
    union { ushort_t u[4]; uint2 v; } ph, pl;
    float xs[4] = {x.x, x.y, x.z, x.w};
    #pragma unroll
    for (int c = 0; c < 4; c++){
        unsigned short h = f2bf(xs[c]);
        ph.u[c] = h;
        pl.u[c] = f2bf(xs[c] - bf2f(h));
    }
    ((uint2*)hi)[i] = ph.v;
    ((uint2*)lo)[i] = pl.v;
}

__global__ __launch_bounds__(256)
void convert_w(const float* __restrict__ Wq, const float* __restrict__ Wk,
               const float* __restrict__ Wv, ushort_t* __restrict__ hi,
               ushort_t* __restrict__ lo)
{
    const float* src = (blockIdx.z==0) ? Wq : (blockIdx.z==1) ? Wk : Wv;
    const int n4 = D_*D_/4;
    int i = blockIdx.x * 256 + threadIdx.x;
    if (i >= n4) return;
    size_t off4 = (size_t)blockIdx.z * n4;
    float4 x = ((const float4*)src)[i];
    union { ushort_t u[4]; uint2 v; } ph, pl;
    float xs[4] = {x.x, x.y, x.z, x.w};
    #pragma unroll
    for (int c = 0; c < 4; c++){
        unsigned short h = f2bf(xs[c]);
        ph.u[c] = h;
        pl.u[c] = f2bf(xs[c] - bf2f(h));
    }
    ((uint2*)hi)[off4 + i] = ph.v;
    ((uint2*)lo)[off4 + i] = pl.v;
}

// ---------------------------------------------------------------------------
// Split-bf16 MFMA GEMM: C[m,n] = sum_k X[m,k] * W[n,k] + bias
// mat 0 -> Q hi/lo bf16, mat 1 -> K hi/lo bf16, mat 2 -> V f32; all [BH,S,DH]
// ---------------------------------------------------------------------------
#define BM 128
#define BN 128
#define BK 32

__global__ __launch_bounds__(256)
void gemm_split(const ushort_t* __restrict__ Ahi, const ushort_t* __restrict__ Alo,
                const ushort_t* __restrict__ Bhi, const ushort_t* __restrict__ Blo,
                const float* __restrict__ bq, const float* __restrict__ bk,
                const float* __restrict__ bv,
                ushort_t* __restrict__ qhi, ushort_t* __restrict__ qlo,
                ushort_t* __restrict__ khi, ushort_t* __restrict__ klo,
                float* __restrict__ outv)
{
    __shared__ ushort_t Ah[BM*BK], Al[BM*BK], Bh[BN*BK], Bl[BN*BK];

    const int tid  = threadIdx.x;
    const int lane = tid & 63, wave = tid >> 6;
    const int m0 = blockIdx.y * BM, n0 = blockIdx.x * BN;
    const int wm = (wave >> 1) * 64, wn = (wave & 1) * 64;

    f32x4 acc[4][4];
    #pragma unroll
    for (int i=0;i<4;i++)
        #pragma unroll
        for (int j=0;j<4;j++) acc[i][j] = (f32x4){0.f,0.f,0.f,0.f};

    const int r0 = tid >> 2, c0 = (tid & 3) * 8;
    const size_t ga0 = (size_t)(m0 + r0)      * D_ + c0;
    const size_t ga1 = (size_t)(m0 + 64 + r0) * D_ + c0;
    const size_t gb0 = (size_t)(n0 + r0)      * D_ + c0;
    const size_t gb1 = (size_t)(n0 + 64 + r0) * D_ + c0;
    const int l0 = wave * 512;
    const int l1 = 2048 + wave * 512;

    const int fr = lane & 15, kc = (lane >> 4) * 8;

    for (int k0 = 0; k0 < D_; k0 += BK) {
        cp16(Ahi + ga0 + k0, Ah + l0);
        cp16(Ahi + ga1 + k0, Ah + l1);
        cp16(Alo + ga0 + k0, Al + l0);
        cp16(Alo + ga1 + k0, Al + l1);
        cp16(Bhi + gb0 + k0, Bh + l0);
        cp16(Bhi + gb1 + k0, Bh + l1);
        cp16(Blo + gb0 + k0, Bl + l0);
        cp16(Blo + gb1 + k0, Bl + l1);
        __syncthreads();

        bf16x8 fah[4], fal[4], fbh[4], fbl[4];
        #pragma unroll
        for (int i = 0; i < 4; i++){
            fah[i] = *(const bf16x8*)&Ah[(wm + i*16 + fr)*BK + kc];
            fal[i] = *(const bf16x8*)&Al[(wm + i*16 + fr)*BK + kc];
            fbh[i] = *(const bf16x8*)&Bh[(wn + i*16 + fr)*BK + kc];
            fbl[i] = *(const bf16x8*)&Bl[(wn + i*16 + fr)*BK + kc];
        }
        #pragma unroll
        for (int i = 0; i < 4; i++)
            #pragma unroll
            for (int j = 0; j < 4; j++){
                acc[i][j] = __builtin_amdgcn_mfma_f32_16x16x32_bf16(fah[i], fbh[j], acc[i][j], 0,0,0);
                acc[i][j] = __builtin_amdgcn_mfma_f32_16x16x32_bf16(fah[i], fbl[j], acc[i][j], 0,0,0);
                acc[i][j] = __builtin_amdgcn_mfma_f32_16x16x32_bf16(fal[i], fbh[j], acc[i][j], 0,0,0);
            }
        __syncthreads();
    }

    const int mat = n0 / D_;   // block-uniform
    const float* bias = (mat==0) ? bq : (mat==1) ? bk : bv;
    const int col = lane & 15, rbase = (lane >> 4) * 4;
    #pragma unroll
    for (int j = 0; j < 4; j++){
        int nn = n0 + wn + j*16 + col - mat*D_;
        int h = nn >> 6, d = nn & 63;
        float bsv = bias[nn];
        #pragma unroll
        for (int i = 0; i < 4; i++){
            #pragma unroll
            for (int r = 0; r < 4; r++){
                int m = m0 + wm + i*16 + rbase + r;
                int bb = m >> 9, s = m & 511;
                size_t idx = (((size_t)bb*H_ + h)*S_ + s)*DH_ + d;
                float val = acc[i][j][r] + bsv;
                if (mat == 2) outv[idx] = val;
                else {
                    ushort_t hv = f2bf(val);
                    ushort_t lv = f2bf(val - bf2f(hv));
                    if (mat == 0){ qhi[idx] = hv; qlo[idx] = lv; }
                    else         { khi[idx] = hv; klo[idx] = lv; }
                }
            }
        }
    }
}

// ---------------------------------------------------------------------------
// V [bh][s][d] f32 -> V^T hi/lo bf16 [bh][d][s] via LDS tile transpose
// ---------------------------------------------------------------------------
__global__ __launch_bounds__(256)
void vt_convert(const float* __restrict__ v, ushort_t* __restrict__ vthi,
                ushort_t* __restrict__ vtlo)
{
    __shared__ float Ts[64][65];
    const int bh = blockIdx.y, s0 = blockIdx.x * 64;
    const float* vb = v + ((size_t)bh * S_ + s0) * DH_;
    const size_t ob = (size_t)bh * DH_ * S_;
    const int t = threadIdx.x;
    const int sr = t >> 4, c4 = (t & 15) * 4;
    #pragma unroll
    for (int p = 0; p < 4; p++){
        float4 val = *(const float4*)&vb[(p*16 + sr)*DH_ + c4];
        Ts[p*16 + sr][c4+0] = val.x;
        Ts[p*16 + sr][c4+1] = val.y;
        Ts[p*16 + sr][c4+2] = val.z;
        Ts[p*16 + sr][c4+3] = val.w;
    }
    __syncthreads();
    #pragma unroll
    for (int p = 0; p < 4; p++){
        int dr = p*16 + sr;
        union { ushort_t u[4]; uint2 w; } hs, ls;
        #pragma unroll
        for (int i = 0; i < 4; i++){
            float x = Ts[c4+i][dr];
            ushort_t h = f2bf(x);
            hs.u[i] = h;
            ls.u[i] = f2bf(x - bf2f(h));
        }
        *(uint2*)&vthi[ob + (size_t)dr*S_ + s0 + c4] = hs.w;
        *(uint2*)&vtlo[ob + (size_t)dr*S_ + s0 + c4] = ls.w;
    }
}

// ---------------------------------------------------------------------------
// MFMA sparsemax attention v4: scores->LDS, wave-local Michelot tau,
// then DENSE MFMA PV (P split hi/lo on the fly, V^T bf16 hi/lo).
// Block = (head, 16 q-rows). 2 barriers total.
// ---------------------------------------------------------------------------
#define SCPAD 524   // float stride; 2-way bank aliasing only (free)

__global__ __launch_bounds__(256)
void attn_mfma(const ushort_t* __restrict__ Qhi, const ushort_t* __restrict__ Qlo,
               const ushort_t* __restrict__ Khi, const ushort_t* __restrict__ Klo,
               const ushort_t* __restrict__ VThi, const ushort_t* __restrict__ VTlo,
               const float* __restrict__ mask, float* __restrict__ out)
{
    __shared__ float sc[16*SCPAD];   // 33.5 KB scores [row][key]
    __shared__ float stau[16];

    const int lane = threadIdx.x & 63;
    const int wave = threadIdx.x >> 6;
    const int fr = lane & 15, quad = lane >> 4;
    const int bh = blockIdx.x >> 5;            // 32 blocks per head
    const int q0 = (blockIdx.x & 31) * 16;
    const int b = bh / H_, h = bh % H_;
    const size_t hb = (size_t)bh * S_ * DH_;
    const int kw0 = wave * 128;                // phase-1 key range

    // ---- Phase 1: QK^T scores -> LDS --------------------------------------
    bf16x8 qh[2], ql[2];
    {
        const ushort_t* qp  = Qhi + hb + (size_t)(q0 + fr)*DH_ + quad*8;
        const ushort_t* qp2 = Qlo + hb + (size_t)(q0 + fr)*DH_ + quad*8;
        qh[0] = *(const bf16x8*)qp;   qh[1] = *(const bf16x8*)(qp + 32);
        ql[0] = *(const bf16x8*)qp2;  ql[1] = *(const bf16x8*)(qp2 + 32);
    }

    f32x4 acc[8];
    #pragma unroll
    for (int j=0;j<8;j++) acc[j] = (f32x4){0.f,0.f,0.f,0.f};

    #pragma unroll
    for (int j=0;j<8;j++){
        const ushort_t* kp  = Khi + hb + (size_t)(kw0 + j*16 + fr)*DH_ + quad*8;
        const ushort_t* kp2 = Klo + hb + (size_t)(kw0 + j*16 + fr)*DH_ + quad*8;
        bf16x8 kh0 = *(const bf16x8*)kp;
        bf16x8 kh1 = *(const bf16x8*)(kp + 32);
        bf16x8 kl0 = *(const bf16x8*)kp2;
        bf16x8 kl1 = *(const bf16x8*)(kp2 + 32);
        acc[j] = __builtin_amdgcn_mfma_f32_16x16x32_bf16(qh[0], kh0, acc[j], 0,0,0);
        acc[j] = __builtin_amdgcn_mfma_f32_16x16x32_bf16(qh[1], kh1, acc[j], 0,0,0);
        acc[j] = __builtin_amdgcn_mfma_f32_16x16x32_bf16(ql[0], kh0, acc[j], 0,0,0);
        acc[j] = __builtin_amdgcn_mfma_f32_16x16x32_bf16(ql[1], kh1, acc[j], 0,0,0);
        acc[j] = __builtin_amdgcn_mfma_f32_16x16x32_bf16(qh[0], kl0, acc[j], 0,0,0);
        acc[j] = __builtin_amdgcn_mfma_f32_16x16x32_bf16(qh[1], kl1, acc[j], 0,0,0);
    }

    const float* mrow = mask + b * S_;
    #pragma unroll
    for (int j=0;j<8;j++){
        float mv = mrow[kw0 + j*16 + fr];
        #pragma unroll
        for (int r=0;r<4;r++)
            sc[(quad*4 + r)*SCPAD + kw0 + j*16 + fr] = acc[j][r]*0.125f + mv;
    }
    __syncthreads();

    // ---- Phase 2: wave-local Michelot tau for rows 4w..4w+3 ---------------
    float z[4][8];
    #pragma unroll
    for (int r=0;r<4;r++){
        const float* p = &sc[(wave*4 + r)*SCPAD + lane*8];
        float4 a = *(const float4*)p;
        float4 c = *(const float4*)(p + 4);
        z[r][0]=a.x; z[r][1]=a.y; z[r][2]=a.z; z[r][3]=a.w;
        z[r][4]=c.x; z[r][5]=c.y; z[r][6]=c.z; z[r][7]=c.w;
    }

    float tau[4];
    {
        float m[4];
        #pragma unroll
        for (int r=0;r<4;r++){
            float mm = z[r][0];
            #pragma unroll
            for (int i=1;i<8;i++) mm = fmaxf(mm, z[r][i]);
            m[r] = mm;
        }
        #pragma unroll
        for (int off=1; off<64; off<<=1){
            #pragma unroll
            for (int r=0;r<4;r++) m[r] = fmaxf(m[r], __shfl_xor(m[r], off, 64));
        }
        #pragma unroll
        for (int r=0;r<4;r++) tau[r] = m[r] - 1.0f;
    }

    for (int it=0; it<16; it++){
        float s[4], k[4];
        #pragma unroll
        for (int r=0;r<4;r++){
            float ss = 0.f, kk = 0.f;
            #pragma unroll
            for (int i=0;i<8;i++){
                float zz = z[r][i];
                if (zz > tau[r]){ ss += zz; kk += 1.f; }
            }
            s[r] = ss; k[r] = kk;
        }
        #pragma unroll
        for (int off=1; off<64; off<<=1){
            #pragma unroll
            for (int r=0;r<4;r++){
                s[r] += __shfl_xor(s[r], off, 64);
                k[r] += __shfl_xor(k[r], off, 64);
            }
        }
        bool any = false;
        #pragma unroll
        for (int r=0;r<4;r++){
            float tn = (s[r] - 1.0f) / k[r];
            any |= (tn != tau[r]);
            tau[r] = tn;
        }
        if (!any) break;
    }
    if (lane == 0){
        #pragma unroll
        for (int r=0;r<4;r++) stau[wave*4 + r] = tau[r];
    }
    __syncthreads();

    // ---- Phase 3: dense MFMA PV. Wave w: rows 0..15 x d-cols [16w,16w+16) --
    const int d0 = wave * 16;
    const float taur = stau[fr];               // row fr's tau
    const ushort_t* vh = VThi + hb + (size_t)(d0 + fr)*S_ + quad*8;
    const ushort_t* vl = VTlo + hb + (size_t)(d0 + fr)*S_ + quad*8;
    const float* arow = &sc[fr*SCPAD + quad*8];

    f32x4 cacc = (f32x4){0.f,0.f,0.f,0.f};
    #pragma unroll
    for (int k0 = 0; k0 < S_; k0 += 32){
        // A-frag: P[row=fr][k=k0+quad*8+j], split hi/lo by truncation
        float4 a = *(const float4*)(arow + k0);
        float4 c = *(const float4*)(arow + k0 + 4);
        float pf[8] = {a.x,a.y,a.z,a.w,c.x,c.y,c.z,c.w};
        union { short s[8]; bf16x8 v; } ph, pl;
        #pragma unroll
        for (int i=0;i<8;i++){
            float p = fmaxf(pf[i] - taur, 0.f);
            unsigned u = __float_as_uint(p);
            ph.s[i] = (short)(u >> 16);
            float rr = p - __uint_as_float(u & 0xFFFF0000u);
            pl.s[i] = (short)(__float_as_uint(rr) >> 16);
        }
        bf16x8 bvh = *(const bf16x8*)(vh + k0);
        bf16x8 bvl = *(const bf16x8*)(vl + k0);
        cacc = __builtin_amdgcn_mfma_f32_16x16x32_bf16(ph.v, bvh, cacc, 0,0,0);
        cacc = __builtin_amdgcn_mfma_f32_16x16x32_bf16(pl.v, bvh, cacc, 0,0,0);
        cacc = __builtin_amdgcn_mfma_f32_16x16x32_bf16(ph.v, bvl, cacc, 0,0,0);
    }

    // C layout: row = quad*4+r (query), col = fr (d offset)
    #pragma unroll
    for (int r=0;r<4;r++)
        out[((size_t)(b*S_ + q0 + quad*4 + r))*D_ + h*DH_ + d0 + fr] = cacc[r];
}

// ---------------------------------------------------------------------------
extern "C" void kernel_launch(void* const* d_in, const int* in_sizes, int n_in,
                              void* d_out, int out_size, void* d_ws, size_t ws_size,
                              hipStream_t stream) {
    const float* hs   = (const float*)d_in[0];
    const float* mask = (const float*)d_in[1];
    const float* Wq   = (const float*)d_in[2];
    const float* bq   = (const float*)d_in[3];
    const float* Wk   = (const float*)d_in[4];
    const float* bk   = (const float*)d_in[5];
    const float* Wv   = (const float*)d_in[6];
    const float* bv   = (const float*)d_in[7];
    float* out = (float*)d_out;

    const size_t per = (size_t)BH_ * S_ * DH_;   // 6291456
    char* w = (char*)d_ws;
    float*    vb  = (float*)w;    w += per*4;
    ushort_t* qhi = (ushort_t*)w; w += per*2;
    ushort_t* qlo = (ushort_t*)w; w += per*2;
    ushort_t* khi = (ushort_t*)w; w += per*2;
    ushort_t* klo = (ushort_t*)w; w += per*2;
    ushort_t* Xhi = (ushort_t*)w; w += per*2;    // reused as VThi after gemm
    ushort_t* Xlo = (ushort_t*)w; w += per*2;    // reused as VTlo after gemm
    ushort_t* Whi = (ushort_t*)w; w += (size_t)NTOT*D_*2;
    ushort_t* Wlo = (ushort_t*)w;
    ushort_t* VThi = Xhi;
    ushort_t* VTlo = Xlo;

    convert_hl<<<(int)(per/4/256), 256, 0, stream>>>(hs, Xhi, Xlo, (int)(per/4));
    convert_w<<<dim3(D_*D_/4/256, 1, 3), 256, 0, stream>>>(Wq, Wk, Wv, Whi, Wlo);

    dim3 ggrid(NTOT/BN, MTOT/BM);   // (18, 64)
    gemm_split<<<ggrid, 256, 0, stream>>>(Xhi, Xlo, Whi, Wlo, bq, bk, bv,
                                          qhi, qlo, khi, klo, vb);

    // transpose+split V (overwrites dead Xhi/Xlo)
    vt_convert<<<dim3(S_/64, BH_), 256, 0, stream>>>(vb, VThi, VTlo);

    attn_mfma<<<BH_*32, 256, 0, stream>>>(qhi, qlo, khi, klo, VThi, VTlo, mask, out);
}

// Round 7
// 335.007 us; speedup vs baseline: 1.2104x; 1.2104x over previous
//
#include <hip/hip_runtime.h>
#include <math.h>

#define B_ 16
#define S_ 512
#define D_ 768
#define H_ 12
#define DH_ 64
#define BH_ (B_*H_)     // 192
#define MTOT (B_*S_)    // 8192
#define NTOT (3*D_)     // 2304

typedef unsigned short ushort_t;
typedef __attribute__((ext_vector_type(8))) short bf16x8;
typedef __attribute__((ext_vector_type(4))) float f32x4;

__device__ __forceinline__ unsigned short f2bf(float x){
    unsigned u = __float_as_uint(x);
    unsigned r = (u + 0x7FFFu + ((u >> 16) & 1u)) >> 16;
    return (unsigned short)r;
}
__device__ __forceinline__ float bf2f(unsigned short b){
    return __uint_as_float(((unsigned)b) << 16);
}

__device__ __forceinline__ void cp16(const void* g, void* l){
    __builtin_amdgcn_global_load_lds(
        (const __attribute__((address_space(1))) unsigned int*)g,
        (__attribute__((address_space(3))) unsigned int*)l, 16, 0, 0);
}

// ---------------------------------------------------------------------------
// f32 -> single bf16 (round-to-nearest), 4 elems/thread
// ---------------------------------------------------------------------------
__global__ __launch_bounds__(256)
void convert_x(const float* __restrict__ src, ushort_t* __restrict__ dst, int n4)
{
    int i = blockIdx.x * 256 + threadIdx.x;
    if (i >= n4) return;
    float4 x = ((const float4*)src)[i];
    union { ushort_t u[4]; uint2 v; } p;
    p.u[0] = f2bf(x.x); p.u[1] = f2bf(x.y);
    p.u[2] = f2bf(x.z); p.u[3] = f2bf(x.w);
    ((uint2*)dst)[i] = p.v;
}

// weights: split hi/lo, all three matrices in one launch
__global__ __launch_bounds__(256)
void convert_w(const float* __restrict__ Wq, const float* __restrict__ Wk,
               const float* __restrict__ Wv, ushort_t* __restrict__ hi,
               ushort_t* __restrict__ lo)
{
    const float* src = (blockIdx.z==0) ? Wq : (blockIdx.z==1) ? Wk : Wv;
    const int n4 = D_*D_/4;
    int i = blockIdx.x * 256 + threadIdx.x;
    if (i >= n4) return;
    size_t off4 = (size_t)blockIdx.z * n4;
    float4 x = ((const float4*)src)[i];
    union { ushort_t u[4]; uint2 v; } ph, pl;
    float xs[4] = {x.x, x.y, x.z, x.w};
    #pragma unroll
    for (int c = 0; c < 4; c++){
        unsigned short h = f2bf(xs[c]);
        ph.u[c] = h;
        pl.u[c] = f2bf(xs[c] - bf2f(h));
    }
    ((uint2*)hi)[off4 + i] = ph.v;
    ((uint2*)lo)[off4 + i] = pl.v;
}

// ---------------------------------------------------------------------------
// MFMA GEMM: C[m,n] = sum_k Xbf[m,k] * W[n,k] + bias; X single bf16, W hi/lo
// (2 MFMAs per tile-pair). mat 0 -> Q hi/lo, 1 -> K hi/lo, 2 -> V f32.
// ---------------------------------------------------------------------------
#define BM 128
#define BN 128
#define BK 32

__global__ __launch_bounds__(256)
void gemm_split(const ushort_t* __restrict__ A,
                const ushort_t* __restrict__ Bhi, const ushort_t* __restrict__ Blo,
                const float* __restrict__ bq, const float* __restrict__ bk,
                const float* __restrict__ bv,
                ushort_t* __restrict__ qhi, ushort_t* __restrict__ qlo,
                ushort_t* __restrict__ khi, ushort_t* __restrict__ klo,
                float* __restrict__ outv)
{
    __shared__ ushort_t Ah[BM*BK], Bh[BN*BK], Bl[BN*BK];  // 24 KB

    const int tid  = threadIdx.x;
    const int lane = tid & 63, wave = tid >> 6;
    const int m0 = blockIdx.y * BM, n0 = blockIdx.x * BN;
    const int wm = (wave >> 1) * 64, wn = (wave & 1) * 64;

    f32x4 acc[4][4];
    #pragma unroll
    for (int i=0;i<4;i++)
        #pragma unroll
        for (int j=0;j<4;j++) acc[i][j] = (f32x4){0.f,0.f,0.f,0.f};

    const int r0 = tid >> 2, c0 = (tid & 3) * 8;
    const size_t ga0 = (size_t)(m0 + r0)      * D_ + c0;
    const size_t ga1 = (size_t)(m0 + 64 + r0) * D_ + c0;
    const size_t gb0 = (size_t)(n0 + r0)      * D_ + c0;
    const size_t gb1 = (size_t)(n0 + 64 + r0) * D_ + c0;
    const int l0 = wave * 512;
    const int l1 = 2048 + wave * 512;

    const int fr = lane & 15, kc = (lane >> 4) * 8;

    for (int k0 = 0; k0 < D_; k0 += BK) {
        cp16(A   + ga0 + k0, Ah + l0);
        cp16(A   + ga1 + k0, Ah + l1);
        cp16(Bhi + gb0 + k0, Bh + l0);
        cp16(Bhi + gb1 + k0, Bh + l1);
        cp16(Blo + gb0 + k0, Bl + l0);
        cp16(Blo + gb1 + k0, Bl + l1);
        __syncthreads();

        bf16x8 fa[4], fbh[4], fbl[4];
        #pragma unroll
        for (int i = 0; i < 4; i++){
            fa[i]  = *(const bf16x8*)&Ah[(wm + i*16 + fr)*BK + kc];
            fbh[i] = *(const bf16x8*)&Bh[(wn + i*16 + fr)*BK + kc];
            fbl[i] = *(const bf16x8*)&Bl[(wn + i*16 + fr)*BK + kc];
        }
        #pragma unroll
        for (int i = 0; i < 4; i++)
            #pragma unroll
            for (int j = 0; j < 4; j++){
                acc[i][j] = __builtin_amdgcn_mfma_f32_16x16x32_bf16(fa[i], fbh[j], acc[i][j], 0,0,0);
                acc[i][j] = __builtin_amdgcn_mfma_f32_16x16x32_bf16(fa[i], fbl[j], acc[i][j], 0,0,0);
            }
        __syncthreads();
    }

    const int mat = n0 / D_;   // block-uniform
    const float* bias = (mat==0) ? bq : (mat==1) ? bk : bv;
    const int col = lane & 15, rbase = (lane >> 4) * 4;
    #pragma unroll
    for (int j = 0; j < 4; j++){
        int nn = n0 + wn + j*16 + col - mat*D_;
        int h = nn >> 6, d = nn & 63;
        float bsv = bias[nn];
        #pragma unroll
        for (int i = 0; i < 4; i++){
            #pragma unroll
            for (int r = 0; r < 4; r++){
                int m = m0 + wm + i*16 + rbase + r;
                int bb = m >> 9, s = m & 511;
                size_t idx = (((size_t)bb*H_ + h)*S_ + s)*DH_ + d;
                float val = acc[i][j][r] + bsv;
                if (mat == 2) outv[idx] = val;
                else {
                    ushort_t hv = f2bf(val);
                    ushort_t lv = f2bf(val - bf2f(hv));
                    if (mat == 0){ qhi[idx] = hv; qlo[idx] = lv; }
                    else         { khi[idx] = hv; klo[idx] = lv; }
                }
            }
        }
    }
}

// ---------------------------------------------------------------------------
// MFMA sparsemax attention (R5 structure + XCD swizzle).
// blockIdx.x = sub*192 + bh  ->  all 32 sub-blocks of head bh on XCD bh%8.
// Phase 1: wave w computes scores for 16 rows x keys [128w,128w+128) -> LDS.
// Phase 2: wave w owns rows 4w..4w+3 (full 512 keys): Michelot tau +
//          ballot-sparse PV, all wave-local; direct store.
// ---------------------------------------------------------------------------
#define SCPAD 524   // float stride; spreads banks across rows

__global__ __launch_bounds__(256)
void attn_mfma(const ushort_t* __restrict__ Qhi, const ushort_t* __restrict__ Qlo,
               const ushort_t* __restrict__ Khi, const ushort_t* __restrict__ Klo,
               const float* __restrict__ V, const float* __restrict__ mask,
               float* __restrict__ out)
{
    __shared__ float sc[16*SCPAD];   // 33.5 KB scores [row][key]

    const int lane = threadIdx.x & 63;
    const int wave = threadIdx.x >> 6;
    const int fr = lane & 15, quad = lane >> 4;
    const int bh = blockIdx.x % BH_;           // XCD-locality swizzle
    const int q0 = (blockIdx.x / BH_) * 16;
    const int b = bh / H_, h = bh % H_;
    const size_t hb = (size_t)bh * S_ * DH_;
    const int kw0 = wave * 128;                // phase-1 key range

    // Q A-fragments: row = fr (q0+fr), k = quad*8 + [0..8)
    bf16x8 qh[2], ql[2];
    {
        const ushort_t* qp  = Qhi + hb + (size_t)(q0 + fr)*DH_ + quad*8;
        const ushort_t* qp2 = Qlo + hb + (size_t)(q0 + fr)*DH_ + quad*8;
        qh[0] = *(const bf16x8*)qp;   qh[1] = *(const bf16x8*)(qp + 32);
        ql[0] = *(const bf16x8*)qp2;  ql[1] = *(const bf16x8*)(qp2 + 32);
    }

    f32x4 acc[8];
    #pragma unroll
    for (int j=0;j<8;j++) acc[j] = (f32x4){0.f,0.f,0.f,0.f};

    #pragma unroll
    for (int j=0;j<8;j++){
        const ushort_t* kp  = Khi + hb + (size_t)(kw0 + j*16 + fr)*DH_ + quad*8;
        const ushort_t* kp2 = Klo + hb + (size_t)(kw0 + j*16 + fr)*DH_ + quad*8;
        bf16x8 kh0 = *(const bf16x8*)kp;
        bf16x8 kh1 = *(const bf16x8*)(kp + 32);
        bf16x8 kl0 = *(const bf16x8*)kp2;
        bf16x8 kl1 = *(const bf16x8*)(kp2 + 32);
        acc[j] = __builtin_amdgcn_mfma_f32_16x16x32_bf16(qh[0], kh0, acc[j], 0,0,0);
        acc[j] = __builtin_amdgcn_mfma_f32_16x16x32_bf16(qh[1], kh1, acc[j], 0,0,0);
        acc[j] = __builtin_amdgcn_mfma_f32_16x16x32_bf16(ql[0], kh0, acc[j], 0,0,0);
        acc[j] = __builtin_amdgcn_mfma_f32_16x16x32_bf16(ql[1], kh1, acc[j], 0,0,0);
        acc[j] = __builtin_amdgcn_mfma_f32_16x16x32_bf16(qh[0], kl0, acc[j], 0,0,0);
        acc[j] = __builtin_amdgcn_mfma_f32_16x16x32_bf16(qh[1], kl1, acc[j], 0,0,0);
    }

    // scale + mask, scatter to LDS (C layout: row=quad*4+r, key=kw0+j*16+fr)
    const float* mrow = mask + b * S_;
    #pragma unroll
    for (int j=0;j<8;j++){
        float mv = mrow[kw0 + j*16 + fr];
        #pragma unroll
        for (int r=0;r<4;r++)
            sc[(quad*4 + r)*SCPAD + kw0 + j*16 + fr] = acc[j][r]*0.125f + mv;
    }
    __syncthreads();

    // wave w owns rows 4w..4w+3; lane l holds keys [8l, 8l+8) of each row
    float z[4][8];
    #pragma unroll
    for (int r=0;r<4;r++){
        const float* p = &sc[(wave*4 + r)*SCPAD + lane*8];
        float4 a = *(const float4*)p;
        float4 c = *(const float4*)(p + 4);
        z[r][0]=a.x; z[r][1]=a.y; z[r][2]=a.z; z[r][3]=a.w;
        z[r][4]=c.x; z[r][5]=c.y; z[r][6]=c.z; z[r][7]=c.w;
    }

    // per-row max (lockstep, 4 independent shfl chains)
    float tau[4];
    {
        float m[4];
        #pragma unroll
        for (int r=0;r<4;r++){
            float mm = z[r][0];
            #pragma unroll
            for (int i=1;i<8;i++) mm = fmaxf(mm, z[r][i]);
            m[r] = mm;
        }
        #pragma unroll
        for (int off=1; off<64; off<<=1){
            #pragma unroll
            for (int r=0;r<4;r++) m[r] = fmaxf(m[r], __shfl_xor(m[r], off, 64));
        }
        #pragma unroll
        for (int r=0;r<4;r++) tau[r] = m[r] - 1.0f;
    }

    // Michelot fixed-point, wave-local lockstep; exits on wave-uniform fixpoint
    for (int it=0; it<16; it++){
        float s[4], k[4];
        #pragma unroll
        for (int r=0;r<4;r++){
            float ss = 0.f, kk = 0.f;
            #pragma unroll
            for (int i=0;i<8;i++){
                float zz = z[r][i];
                if (zz > tau[r]){ ss += zz; kk += 1.f; }
            }
            s[r] = ss; k[r] = kk;
        }
        #pragma unroll
        for (int off=1; off<64; off<<=1){
            #pragma unroll
            for (int r=0;r<4;r++){
                s[r] += __shfl_xor(s[r], off, 64);
                k[r] += __shfl_xor(k[r], off, 64);
            }
        }
        bool any = false;
        #pragma unroll
        for (int r=0;r<4;r++){
            float tn = (s[r] - 1.0f) / k[r];
            any |= (tn != tau[r]);
            tau[r] = tn;
        }
        if (!any) break;
    }

    // PV: ballot-sparse gather; key = 8*src + i; V row read coalesced (256B)
    float ctx[4] = {0.f, 0.f, 0.f, 0.f};
    const float* vb = V + hb;
    #pragma unroll
    for (int r=0;r<4;r++){
        #pragma unroll
        for (int i=0;i<8;i++){
            float p = fmaxf(z[r][i] - tau[r], 0.f);
            unsigned long long mk = __ballot(p > 0.f);
            while (mk){
                int src = __ffsll((long long)mk) - 1;
                mk &= mk - 1;
                float pv = __shfl(p, src, 64);
                ctx[r] += pv * vb[(size_t)(src*8 + i)*DH_ + lane];
            }
        }
    }

    #pragma unroll
    for (int r=0;r<4;r++)
        out[((size_t)(b*S_ + q0 + wave*4 + r))*D_ + h*DH_ + lane] = ctx[r];
}

// ---------------------------------------------------------------------------
extern "C" void kernel_launch(void* const* d_in, const int* in_sizes, int n_in,
                              void* d_out, int out_size, void* d_ws, size_t ws_size,
                              hipStream_t stream) {
    const float* hs   = (const float*)d_in[0];
    const float* mask = (const float*)d_in[1];
    const float* Wq   = (const float*)d_in[2];
    const float* bq   = (const float*)d_in[3];
    const float* Wk   = (const float*)d_in[4];
    const float* bk   = (const float*)d_in[5];
    const float* Wv   = (const float*)d_in[6];
    const float* bv   = (const float*)d_in[7];
    float* out = (float*)d_out;

    const size_t per = (size_t)BH_ * S_ * DH_;   // 6291456
    char* w = (char*)d_ws;
    float*    vb  = (float*)w;    w += per*4;
    ushort_t* qhi = (ushort_t*)w; w += per*2;
    ushort_t* qlo = (ushort_t*)w; w += per*2;
    ushort_t* khi = (ushort_t*)w; w += per*2;
    ushort_t* klo = (ushort_t*)w; w += per*2;
    ushort_t* Xbf = (ushort_t*)w; w += per*2;
    ushort_t* Whi = (ushort_t*)w; w += (size_t)NTOT*D_*2;
    ushort_t* Wlo = (ushort_t*)w;

    convert_x<<<(int)(per/4/256), 256, 0, stream>>>(hs, Xbf, (int)(per/4));
    convert_w<<<dim3(D_*D_/4/256, 1, 3), 256, 0, stream>>>(Wq, Wk, Wv, Whi, Wlo);

    dim3 ggrid(NTOT/BN, MTOT/BM);   // (18, 64)
    gemm_split<<<ggrid, 256, 0, stream>>>(Xbf, Whi, Wlo, bq, bk, bv,
                                          qhi, qlo, khi, klo, vb);

    attn_mfma<<<BH_*32, 256, 0, stream>>>(qhi, qlo, khi, klo, vb, mask, out);
}